// Round 13
// baseline (1086.656 us; speedup 1.0000x reference)
//
#include <hip/hip_runtime.h>

#define B 4
#define N1 2048
#define N2 8192
#define C1 128
#define C2 64
#define K 15
#define F 128
#define S 16

// ---------------------------------------------------------------------------
// kNN: unchanged (R8-validated semantics, verified passing rounds 0/5-12).
// ---------------------------------------------------------------------------
__global__ __launch_bounds__(512) void knn_kernel(
    const float* __restrict__ xyz1, const float* __restrict__ xyz2,
    unsigned short* __restrict__ nn_idx) {
#pragma clang fp contract(off)
  __shared__ float sx[N1], sy[N1], sz[N1];     // 24 KB
  __shared__ float s_cd[16][522];              // 33.4 KB (row 522: banks spread)
  __shared__ unsigned short s_ci[16][522];     // 16.7 KB
  const int b = blockIdx.y;
  const int q0 = blockIdx.x * 16;
  const int tid = threadIdx.x;

  const float* p1 = xyz1 + (size_t)b * N1 * 3;
  for (int i = tid; i < N1; i += 512) {
    sx[i] = p1[i * 3 + 0];
    sy[i] = p1[i * 3 + 1];
    sz[i] = p1[i * 3 + 2];
  }
  __syncthreads();

  const int wv = tid >> 6;
  const int lane = tid & 63;
  const int q = lane & 15;
  const int sub = lane >> 4;
  const float* p2 = xyz2 + ((size_t)b * N2 + q0 + q) * 3;
  const float qx = p2[0], qy = p2[1], qz = p2[2];

  float bd[S];
  int bi[S];
#pragma unroll
  for (int j = 0; j < S; ++j) { bd[j] = 3.4e38f; bi[j] = 0x7fffffff; }

  const int i0 = wv * 256 + sub;
  for (int ii = 0; ii < 64; ++ii) {
    const int i = i0 + (ii << 2);
    float dx = qx - sx[i];
    float dy = qy - sy[i];
    float dz = qz - sz[i];
    float d = dx * dx;
    d = d + dy * dy;
    d = d + dz * dz;
    if (d < bd[S - 1]) {   // ascending subset scan: strict < == lex (d, idx)
      bd[S - 1] = d;
      bi[S - 1] = i;
#pragma unroll
      for (int j = S - 1; j > 0; --j) {
        if (bd[j] < bd[j - 1]) {
          float td = bd[j]; bd[j] = bd[j - 1]; bd[j - 1] = td;
          int ti = bi[j]; bi[j] = bi[j - 1]; bi[j - 1] = ti;
        }
      }
    }
  }
  {
    const int ls = (wv * 4 + sub) * 16;
#pragma unroll
    for (int j = 0; j < S; ++j) {
      s_cd[q][ls + j] = bd[j];
      s_ci[q][ls + j] = (unsigned short)bi[j];
    }
  }
  __syncthreads();

  // Tree merge: L lists -> L/2, in-place (slot m), barrier-separated.
  for (int L = 32; L >= 4; L >>= 1) {
    const int half = L >> 1;
    const int nact = 16 * half;
    const int valid = tid < nact;
    float od[16];
    int oi[16];
    int q2 = 0, m = 0;
    if (valid) {
      q2 = tid / half;
      m = tid - q2 * half;
      int pa = (2 * m) * 16, ea = pa + 16;
      int pb = ea, eb = pb + 16;
#pragma unroll
      for (int j = 0; j < 16; ++j) {
        const int a_ok = pa < ea, b_ok = pb < eb;
        const int ra = a_ok ? pa : ea - 1;
        const int rb = b_ok ? pb : eb - 1;
        float da = s_cd[q2][ra];
        int ia = (int)s_ci[q2][ra];
        float db = s_cd[q2][rb];
        int ib = (int)s_ci[q2][rb];
        const int ta = a_ok && (!b_ok || da < db || (da == db && ia < ib));
        od[j] = ta ? da : db;
        oi[j] = ta ? ia : ib;
        pa += ta;
        pb += !ta;
      }
    }
    __syncthreads();
    if (valid) {
#pragma unroll
      for (int j = 0; j < 16; ++j) {
        s_cd[q2][m * 16 + j] = od[j];
        s_ci[q2][m * 16 + j] = (unsigned short)oi[j];
      }
    }
    __syncthreads();
  }

  // Final round: merge lists 0,1 -> global output (16 threads).
  if (tid < 16) {
    const int q2 = tid;
    int pa = 0, ea = 16, pb = 16, eb = 32;
    unsigned short* op = nn_idx + ((size_t)b * N2 + q0 + q2) * S;
#pragma unroll
    for (int j = 0; j < 16; ++j) {
      const int a_ok = pa < ea, b_ok = pb < eb;
      const int ra = a_ok ? pa : ea - 1;
      const int rb = b_ok ? pb : eb - 1;
      float da = s_cd[q2][ra];
      int ia = (int)s_ci[q2][ra];
      float db = s_cd[q2][rb];
      int ib = (int)s_ci[q2][rb];
      const int ta = a_ok && (!b_ok || da < db || (da == db && ia < ib));
      op[j] = (unsigned short)(ta ? ia : ib);
      pa += ta;
      pb += !ta;
    }
  }
}

// ---------------------------------------------------------------------------
// Conv, round 13: R9's VERIFIED 512-thread/4-channel mapping (passed bit-
// exact 0.03125) with R0's VERBATIM loop structure (plain rolled k-loop,
// two barriers/k, single s_wf buffer). R9's 807us came from its bundled
// double-buffer + force-unrolled staging loop (the R5 anti-pattern), not
// the mapping. Per-thread state halves vs R0: wfr[15][4]=60 (was 120),
// acc[4]=16 (was 32) => combined regs ~160-170 => 3 waves/SIMD (R0: ~232
// => 2). Per-thread VALU halves; total issue work unchanged, spread over
// 2x waves with R0-grade ILP. Respects every learned constraint: one
// monolithic phase B, no chunk loop, no launch-bounds cap, no dbuf.
// ---------------------------------------------------------------------------
__global__ __launch_bounds__(512) void conv_kernel(
    const float* __restrict__ xyz1, const float* __restrict__ feat1,
    const float* __restrict__ xyz2, const float* __restrict__ feat2,
    const float* __restrict__ kp, const float* __restrict__ W,
    const unsigned short* __restrict__ nn_idx, float* __restrict__ out) {
  __shared__ __align__(16) float s_buf[5184];   // 20.7 KB, aliased regions:
  int (*s_idx)[S] = (int(*)[S])(s_buf);                  // [0, 256)
  float (*s_rel)[S][3] = (float(*)[S][3])(s_buf + 256);  // [256, 1024)
  float (*s_w)[260] = (float(*)[260])(s_buf + 1024);     // [1024, 5184)
  float (*s_red)[16][132] = (float(*)[16][132])(s_buf);  // [0, 4224) alias
  __shared__ float s_wf[C1][20];               // 10 KB (single buffer)
  __shared__ float s_kp[K * 3];

  const int b = blockIdx.y;
  const int q0 = blockIdx.x * 16;
  const int tid = threadIdx.x;

  if (tid < K * 3) s_kp[tid] = kp[tid];
  if (tid < 256)
    s_idx[tid >> 4][tid & 15] = (int)nn_idx[((size_t)b * N2 + q0) * S + tid];
  __syncthreads();

  if (tid < 256) {
    int q = tid >> 4, s = tid & 15;
    int i = s_idx[q][s];
    const float* pn = xyz1 + ((size_t)b * N1 + i) * 3;
    const float* pq = xyz2 + ((size_t)b * N2 + q0 + q) * 3;
    s_rel[q][s][0] = pn[0] - pq[0];
    s_rel[q][s][1] = pn[1] - pq[1];
    s_rel[q][s][2] = pn[2] - pq[2];
  }
  __syncthreads();

  for (int t = tid; t < 16 * S * K; t += 512) {
    int q = t / (S * K);
    int r = t - q * (S * K);
    int s = r / K;
    int k = r - s * K;
    float rx = s_rel[q][s][0] - s_kp[k * 3 + 0];
    float ry = s_rel[q][s][1] - s_kp[k * 3 + 1];
    float rz = s_rel[q][s][2] - s_kp[k * 3 + 2];
    float d = sqrtf(fmaxf(rx * rx + ry * ry + rz * rz, 1e-12f));
    s_w[q][s * 16 + k] = fmaxf(0.0f, 1.0f - d / 0.2f);
  }
  __syncthreads();

  const int q = tid & 15;
  const int cg = tid >> 4;          // 0..31: this thread owns c = cg*4..+3

  float wfr[K][4];
#pragma unroll
  for (int k = 0; k < K; ++k)
#pragma unroll
    for (int j = 0; j < 4; ++j) wfr[k][j] = 0.0f;

  // Phase B: per (q,k,c) fmac chain over s identical to R0/R7 (verified
  // bit-identical in R9).
  for (int s = 0; s < S; ++s) {
    int i = s_idx[q][s];
    float4 n0 = *((const float4*)(feat1 + ((size_t)b * N1 + i) * C1) + cg);
    const float4* wr = (const float4*)(&s_w[q][s * 16]);
    float4 w0 = wr[0], w1 = wr[1], w2 = wr[2], w3 = wr[3];
    float wk[16] = {w0.x, w0.y, w0.z, w0.w, w1.x, w1.y, w1.z, w1.w,
                    w2.x, w2.y, w2.z, w2.w, w3.x, w3.y, w3.z, w3.w};
#pragma unroll
    for (int k = 0; k < K; ++k) {
      float w = wk[k];
      wfr[k][0] += w * n0.x;
      wfr[k][1] += w * n0.y;
      wfr[k][2] += w * n0.z;
      wfr[k][3] += w * n0.w;
    }
  }

  const int qg = tid >> 7;          // 0..3: q-group of 4
  const int cs = (tid >> 5) & 3;    // 0..3: c-slice of 32
  const int fg = tid & 31;          // f-group (float4)
  float4 acc[4];
#pragma unroll
  for (int qi = 0; qi < 4; ++qi) acc[qi] = make_float4(0.f, 0.f, 0.f, 0.f);

  // GEMM: R0's exact structure (rolled loop, two barriers, single buffer).
  for (int k = 0; k < K; ++k) {
    __syncthreads();
#pragma unroll
    for (int j = 0; j < 4; ++j) s_wf[cg * 4 + j][q] = wfr[k][j];
    __syncthreads();

    const float4* Wk4 = (const float4*)(W + (size_t)k * C1 * F) + fg;
#pragma unroll 4
    for (int c2 = 0; c2 < 32; ++c2) {
      int c = cs * 32 + c2;
      float4 wa = *(const float4*)(&s_wf[c][qg * 4]);
      float4 w4 = Wk4[c * 32];
      acc[0].x += wa.x * w4.x; acc[0].y += wa.x * w4.y;
      acc[0].z += wa.x * w4.z; acc[0].w += wa.x * w4.w;
      acc[1].x += wa.y * w4.x; acc[1].y += wa.y * w4.y;
      acc[1].z += wa.y * w4.z; acc[1].w += wa.y * w4.w;
      acc[2].x += wa.z * w4.x; acc[2].y += wa.z * w4.y;
      acc[2].z += wa.z * w4.z; acc[2].w += wa.z * w4.w;
      acc[3].x += wa.w * w4.x; acc[3].y += wa.w * w4.y;
      acc[3].z += wa.w * w4.z; acc[3].w += wa.w * w4.w;
    }
  }

  // 2-pass reduction into s_red[2][16][132] (aliases s_idx/s_rel/s_w — all
  // dead since phase B, many barriers ago). Sum order ((a0+a1)+a2)+a3
  // preserved => bit-identical. Verified in R9 with this thread mapping.
  const int qq = tid >> 5;         // 0..15
  const int fj = tid & 31;

  __syncthreads();   // last GEMM's s_wf reads complete block-wide
  if (cs < 2) {
#pragma unroll
    for (int qi = 0; qi < 4; ++qi)
      *(float4*)(&s_red[cs][qg * 4 + qi][fg * 4]) = acc[qi];
  }
  __syncthreads();

  float4 s01;
  {
    float4 a0 = *(const float4*)&s_red[0][qq][fj * 4];
    float4 a1 = *(const float4*)&s_red[1][qq][fj * 4];
    s01.x = a0.x + a1.x; s01.y = a0.y + a1.y;
    s01.z = a0.z + a1.z; s01.w = a0.w + a1.w;
  }
  __syncthreads();
  if (cs >= 2) {
#pragma unroll
    for (int qi = 0; qi < 4; ++qi)
      *(float4*)(&s_red[cs - 2][qg * 4 + qi][fg * 4]) = acc[qi];
  }
  __syncthreads();
  {
    float4 a2 = *(const float4*)&s_red[0][qq][fj * 4];
    float4 a3 = *(const float4*)&s_red[1][qq][fj * 4];
    float4 v;
    v.x = fmaxf((s01.x + a2.x) + a3.x, 0.0f);
    v.y = fmaxf((s01.y + a2.y) + a3.y, 0.0f);
    v.z = fmaxf((s01.z + a2.z) + a3.z, 0.0f);
    v.w = fmaxf((s01.w + a2.w) + a3.w, 0.0f);
    ((float4*)(out + ((size_t)b * N2 + q0 + qq) * (F + C2)))[fj] = v;
  }

  if (tid < 256) {
    int qq2 = tid >> 4;
    int j = tid & 15;
    float4 v = ((const float4*)(feat2 + ((size_t)b * N2 + q0 + qq2) * C2))[j];
    ((float4*)(out + ((size_t)b * N2 + q0 + qq2) * (F + C2) + F))[j] = v;
  }
}

extern "C" void kernel_launch(void* const* d_in, const int* in_sizes, int n_in,
                              void* d_out, int out_size, void* d_ws, size_t ws_size,
                              hipStream_t stream) {
  const float* xyz1 = (const float*)d_in[0];
  const float* feat1 = (const float*)d_in[1];
  const float* xyz2 = (const float*)d_in[2];
  const float* feat2 = (const float*)d_in[3];
  const float* kp = (const float*)d_in[4];
  const float* Wm = (const float*)d_in[5];
  float* out = (float*)d_out;

  unsigned short* nn_idx = (unsigned short*)d_ws;   // 1 MB (known-safe)

  knn_kernel<<<dim3(N2 / 16, B), 512, 0, stream>>>(xyz1, xyz2, nn_idx);
  conv_kernel<<<dim3(N2 / 16, B), 512, 0, stream>>>(xyz1, feat1, xyz2, feat2,
                                                    kp, Wm, nn_idx, out);
}

// Round 14
// 532.640 us; speedup vs baseline: 2.0401x; 2.0401x over previous
//
#include <hip/hip_runtime.h>

#define B 4
#define N1 2048
#define N2 8192
#define C1 128
#define C2 64
#define K 15
#define F 128
#define S 16

// ---------------------------------------------------------------------------
// kNN, round 14: identical semantics to the R8-validated kernel (same
// distance formula under fp contract(off), same lex-(d,idx) scan/merge),
// with ONE change: xyz1 is read directly from global (24 KB/batch, fits
// the 32 KB L1; broadcast reads are L1-served) instead of being staged in
// 24 KB of LDS. LDS 74.75 -> 50.1 KB => 3 blocks/CU (was 2), +50% waves
// to hide the divergent insert-scan latency. Values bit-identical.
// ---------------------------------------------------------------------------
__global__ __launch_bounds__(512) void knn_kernel(
    const float* __restrict__ xyz1, const float* __restrict__ xyz2,
    unsigned short* __restrict__ nn_idx) {
#pragma clang fp contract(off)
  __shared__ float s_cd[16][522];              // 33.4 KB (row 522: banks spread)
  __shared__ unsigned short s_ci[16][522];     // 16.7 KB
  const int b = blockIdx.y;
  const int q0 = blockIdx.x * 16;
  const int tid = threadIdx.x;

  const float* p1 = xyz1 + (size_t)b * N1 * 3;

  const int wv = tid >> 6;
  const int lane = tid & 63;
  const int q = lane & 15;
  const int sub = lane >> 4;
  const float* p2 = xyz2 + ((size_t)b * N2 + q0 + q) * 3;
  const float qx = p2[0], qy = p2[1], qz = p2[2];

  float bd[S];
  int bi[S];
#pragma unroll
  for (int j = 0; j < S; ++j) { bd[j] = 3.4e38f; bi[j] = 0x7fffffff; }

  const int i0 = wv * 256 + sub;
  for (int ii = 0; ii < 64; ++ii) {
    const int i = i0 + (ii << 2);
    float x = p1[i * 3 + 0];
    float y = p1[i * 3 + 1];
    float z = p1[i * 3 + 2];
    float dx = qx - x;
    float dy = qy - y;
    float dz = qz - z;
    float d = dx * dx;
    d = d + dy * dy;
    d = d + dz * dz;
    if (d < bd[S - 1]) {   // ascending subset scan: strict < == lex (d, idx)
      bd[S - 1] = d;
      bi[S - 1] = i;
#pragma unroll
      for (int j = S - 1; j > 0; --j) {
        if (bd[j] < bd[j - 1]) {
          float td = bd[j]; bd[j] = bd[j - 1]; bd[j - 1] = td;
          int ti = bi[j]; bi[j] = bi[j - 1]; bi[j - 1] = ti;
        }
      }
    }
  }
  {
    const int ls = (wv * 4 + sub) * 16;
#pragma unroll
    for (int j = 0; j < S; ++j) {
      s_cd[q][ls + j] = bd[j];
      s_ci[q][ls + j] = (unsigned short)bi[j];
    }
  }
  __syncthreads();

  // Tree merge: L lists -> L/2, in-place (slot m), barrier-separated.
  for (int L = 32; L >= 4; L >>= 1) {
    const int half = L >> 1;
    const int nact = 16 * half;
    const int valid = tid < nact;
    float od[16];
    int oi[16];
    int q2 = 0, m = 0;
    if (valid) {
      q2 = tid / half;
      m = tid - q2 * half;
      int pa = (2 * m) * 16, ea = pa + 16;
      int pb = ea, eb = pb + 16;
#pragma unroll
      for (int j = 0; j < 16; ++j) {
        const int a_ok = pa < ea, b_ok = pb < eb;
        const int ra = a_ok ? pa : ea - 1;
        const int rb = b_ok ? pb : eb - 1;
        float da = s_cd[q2][ra];
        int ia = (int)s_ci[q2][ra];
        float db = s_cd[q2][rb];
        int ib = (int)s_ci[q2][rb];
        const int ta = a_ok && (!b_ok || da < db || (da == db && ia < ib));
        od[j] = ta ? da : db;
        oi[j] = ta ? ia : ib;
        pa += ta;
        pb += !ta;
      }
    }
    __syncthreads();
    if (valid) {
#pragma unroll
      for (int j = 0; j < 16; ++j) {
        s_cd[q2][m * 16 + j] = od[j];
        s_ci[q2][m * 16 + j] = (unsigned short)oi[j];
      }
    }
    __syncthreads();
  }

  // Final round: merge lists 0,1 -> global output (16 threads).
  if (tid < 16) {
    const int q2 = tid;
    int pa = 0, ea = 16, pb = 16, eb = 32;
    unsigned short* op = nn_idx + ((size_t)b * N2 + q0 + q2) * S;
#pragma unroll
    for (int j = 0; j < 16; ++j) {
      const int a_ok = pa < ea, b_ok = pb < eb;
      const int ra = a_ok ? pa : ea - 1;
      const int rb = b_ok ? pb : eb - 1;
      float da = s_cd[q2][ra];
      int ia = (int)s_ci[q2][ra];
      float db = s_cd[q2][rb];
      int ib = (int)s_ci[q2][rb];
      const int ta = a_ok && (!b_ok || da < db || (da == db && ia < ib));
      op[j] = (unsigned short)(ta ? ia : ib);
      pa += ta;
      pb += !ta;
    }
  }
}

// ---------------------------------------------------------------------------
// Conv: VERBATIM R7 (best verified: 370 us, 112 VGPR, no spill, absmax
// 0.03125). Nine restructures (R5/R6/R8-R13) all regressed: this monolith
// at 256 threads / no reg-cap is the allocator's local optimum
// ({2 waves/SIMD x high ILP}); conv is closed at this shape.
// ---------------------------------------------------------------------------
__global__ __launch_bounds__(256) void conv_kernel(
    const float* __restrict__ xyz1, const float* __restrict__ feat1,
    const float* __restrict__ xyz2, const float* __restrict__ feat2,
    const float* __restrict__ kp, const float* __restrict__ W,
    const unsigned short* __restrict__ nn_idx, float* __restrict__ out) {
  __shared__ __align__(16) float s_buf[5184];   // 20.7 KB, aliased regions:
  int (*s_idx)[S] = (int(*)[S])(s_buf);                  // [0, 256)
  float (*s_rel)[S][3] = (float(*)[S][3])(s_buf + 256);  // [256, 1024)
  float (*s_w)[260] = (float(*)[260])(s_buf + 1024);     // [1024, 5184)
  float (*s_red)[16][132] = (float(*)[16][132])(s_buf);  // [0, 4224) alias
  __shared__ float s_wf[C1][20];               // 10 KB (live through k-loop)
  __shared__ float s_kp[K * 3];

  const int b = blockIdx.y;
  const int q0 = blockIdx.x * 16;
  const int tid = threadIdx.x;

  if (tid < K * 3) s_kp[tid] = kp[tid];
  s_idx[tid >> 4][tid & 15] = (int)nn_idx[((size_t)b * N2 + q0) * S + tid];
  __syncthreads();

  {
    int q = tid >> 4, s = tid & 15;
    int i = s_idx[q][s];
    const float* pn = xyz1 + ((size_t)b * N1 + i) * 3;
    const float* pq = xyz2 + ((size_t)b * N2 + q0 + q) * 3;
    s_rel[q][s][0] = pn[0] - pq[0];
    s_rel[q][s][1] = pn[1] - pq[1];
    s_rel[q][s][2] = pn[2] - pq[2];
  }
  __syncthreads();

  for (int t = tid; t < 16 * S * K; t += 256) {
    int q = t / (S * K);
    int r = t - q * (S * K);
    int s = r / K;
    int k = r - s * K;
    float rx = s_rel[q][s][0] - s_kp[k * 3 + 0];
    float ry = s_rel[q][s][1] - s_kp[k * 3 + 1];
    float rz = s_rel[q][s][2] - s_kp[k * 3 + 2];
    float d = sqrtf(fmaxf(rx * rx + ry * ry + rz * rz, 1e-12f));
    s_w[q][s * 16 + k] = fmaxf(0.0f, 1.0f - d / 0.2f);
  }
  __syncthreads();

  const int q = tid & 15;
  const int cg = tid >> 4;

  float wfr[K][8];
#pragma unroll
  for (int k = 0; k < K; ++k)
#pragma unroll
    for (int j = 0; j < 8; ++j) wfr[k][j] = 0.0f;

  for (int s = 0; s < S; ++s) {
    int i = s_idx[q][s];
    const float4* fp = (const float4*)(feat1 + ((size_t)b * N1 + i) * C1) + cg * 2;
    float4 n0 = fp[0];
    float4 n1 = fp[1];
    const float4* wr = (const float4*)(&s_w[q][s * 16]);
    float4 w0 = wr[0], w1 = wr[1], w2 = wr[2], w3 = wr[3];
    float wk[16] = {w0.x, w0.y, w0.z, w0.w, w1.x, w1.y, w1.z, w1.w,
                    w2.x, w2.y, w2.z, w2.w, w3.x, w3.y, w3.z, w3.w};
#pragma unroll
    for (int k = 0; k < K; ++k) {
      float w = wk[k];
      wfr[k][0] += w * n0.x;
      wfr[k][1] += w * n0.y;
      wfr[k][2] += w * n0.z;
      wfr[k][3] += w * n0.w;
      wfr[k][4] += w * n1.x;
      wfr[k][5] += w * n1.y;
      wfr[k][6] += w * n1.z;
      wfr[k][7] += w * n1.w;
    }
  }

  const int qg = tid >> 7;
  const int cs = (tid >> 5) & 3;
  const int fg = tid & 31;
  float4 acc[8];
#pragma unroll
  for (int qi = 0; qi < 8; ++qi) acc[qi] = make_float4(0.f, 0.f, 0.f, 0.f);

  for (int k = 0; k < K; ++k) {
    __syncthreads();
#pragma unroll
    for (int j = 0; j < 8; ++j) s_wf[cg * 8 + j][q] = wfr[k][j];
    __syncthreads();

    const float4* Wk4 = (const float4*)(W + (size_t)k * C1 * F) + fg;
#pragma unroll 4
    for (int c2 = 0; c2 < 32; ++c2) {
      int c = cs * 32 + c2;
      float4 wa = *(const float4*)(&s_wf[c][qg * 8 + 0]);
      float4 wb = *(const float4*)(&s_wf[c][qg * 8 + 4]);
      float4 w4 = Wk4[c * 32];
      acc[0].x += wa.x * w4.x; acc[0].y += wa.x * w4.y;
      acc[0].z += wa.x * w4.z; acc[0].w += wa.x * w4.w;
      acc[1].x += wa.y * w4.x; acc[1].y += wa.y * w4.y;
      acc[1].z += wa.y * w4.z; acc[1].w += wa.y * w4.w;
      acc[2].x += wa.z * w4.x; acc[2].y += wa.z * w4.y;
      acc[2].z += wa.z * w4.z; acc[2].w += wa.z * w4.w;
      acc[3].x += wa.w * w4.x; acc[3].y += wa.w * w4.y;
      acc[3].z += wa.w * w4.z; acc[3].w += wa.w * w4.w;
      acc[4].x += wb.x * w4.x; acc[4].y += wb.x * w4.y;
      acc[4].z += wb.x * w4.z; acc[4].w += wb.x * w4.w;
      acc[5].x += wb.y * w4.x; acc[5].y += wb.y * w4.y;
      acc[5].z += wb.y * w4.z; acc[5].w += wb.y * w4.w;
      acc[6].x += wb.z * w4.x; acc[6].y += wb.z * w4.y;
      acc[6].z += wb.z * w4.z; acc[6].w += wb.z * w4.w;
      acc[7].x += wb.w * w4.x; acc[7].y += wb.w * w4.y;
      acc[7].z += wb.w * w4.z; acc[7].w += wb.w * w4.w;
    }
  }

  // 2-pass reduction into s_red[2][16][132] (aliases s_idx/s_rel/s_w — all
  // dead, >=30 barriers before the first write here). Summation order
  // ((a0+a1)+a2)+a3 preserved => bit-identical. Validated R5-R7.
  const int qq0 = tid >> 5;        // item 0: qq 0..7
  const int qq1 = 8 + (tid >> 5);  // item 1: qq 8..15
  const int fj = tid & 31;

  if (cs < 2) {
#pragma unroll
    for (int qi = 0; qi < 8; ++qi)
      *(float4*)(&s_red[cs][qg * 8 + qi][fg * 4]) = acc[qi];
  }
  __syncthreads();

  float4 s01_0, s01_1;
  {
    float4 a0 = *(const float4*)&s_red[0][qq0][fj * 4];
    float4 a1 = *(const float4*)&s_red[1][qq0][fj * 4];
    s01_0.x = a0.x + a1.x; s01_0.y = a0.y + a1.y;
    s01_0.z = a0.z + a1.z; s01_0.w = a0.w + a1.w;
    float4 b0 = *(const float4*)&s_red[0][qq1][fj * 4];
    float4 b1 = *(const float4*)&s_red[1][qq1][fj * 4];
    s01_1.x = b0.x + b1.x; s01_1.y = b0.y + b1.y;
    s01_1.z = b0.z + b1.z; s01_1.w = b0.w + b1.w;
  }
  __syncthreads();
  if (cs >= 2) {
#pragma unroll
    for (int qi = 0; qi < 8; ++qi)
      *(float4*)(&s_red[cs - 2][qg * 8 + qi][fg * 4]) = acc[qi];
  }
  __syncthreads();
  {
    float4 a2 = *(const float4*)&s_red[0][qq0][fj * 4];
    float4 a3 = *(const float4*)&s_red[1][qq0][fj * 4];
    float4 v;
    v.x = fmaxf((s01_0.x + a2.x) + a3.x, 0.0f);
    v.y = fmaxf((s01_0.y + a2.y) + a3.y, 0.0f);
    v.z = fmaxf((s01_0.z + a2.z) + a3.z, 0.0f);
    v.w = fmaxf((s01_0.w + a2.w) + a3.w, 0.0f);
    ((float4*)(out + ((size_t)b * N2 + q0 + qq0) * (F + C2)))[fj] = v;
    float4 b2 = *(const float4*)&s_red[0][qq1][fj * 4];
    float4 b3 = *(const float4*)&s_red[1][qq1][fj * 4];
    float4 u;
    u.x = fmaxf((s01_1.x + b2.x) + b3.x, 0.0f);
    u.y = fmaxf((s01_1.y + b2.y) + b3.y, 0.0f);
    u.z = fmaxf((s01_1.z + b2.z) + b3.z, 0.0f);
    u.w = fmaxf((s01_1.w + b2.w) + b3.w, 0.0f);
    ((float4*)(out + ((size_t)b * N2 + q0 + qq1) * (F + C2)))[fj] = u;
  }

  {
    int qq = tid >> 4;
    int j = tid & 15;
    float4 v = ((const float4*)(feat2 + ((size_t)b * N2 + q0 + qq) * C2))[j];
    ((float4*)(out + ((size_t)b * N2 + q0 + qq) * (F + C2) + F))[j] = v;
  }
}

extern "C" void kernel_launch(void* const* d_in, const int* in_sizes, int n_in,
                              void* d_out, int out_size, void* d_ws, size_t ws_size,
                              hipStream_t stream) {
  const float* xyz1 = (const float*)d_in[0];
  const float* feat1 = (const float*)d_in[1];
  const float* xyz2 = (const float*)d_in[2];
  const float* feat2 = (const float*)d_in[3];
  const float* kp = (const float*)d_in[4];
  const float* Wm = (const float*)d_in[5];
  float* out = (float*)d_out;

  unsigned short* nn_idx = (unsigned short*)d_ws;   // 1 MB (known-safe)

  knn_kernel<<<dim3(N2 / 16, B), 512, 0, stream>>>(xyz1, xyz2, nn_idx);
  conv_kernel<<<dim3(N2 / 16, B), 256, 0, stream>>>(xyz1, feat1, xyz2, feat2,
                                                    kp, Wm, nn_idx, out);
}

// Round 15
// 529.434 us; speedup vs baseline: 2.0525x; 1.0061x over previous
//
#include <hip/hip_runtime.h>

#define B 4
#define N1 2048
#define N2 8192
#define C1 128
#define C2 64
#define K 15
#define F 128
#define S 16

// ---------------------------------------------------------------------------
// kNN, round 15: 32 queries/block x 16 lists of 128 points (was 16q x 32
// lists of 64). Wave = 32q x 2 lists; list = wv*2+sub scans i = list+16*ii
// ascending (disjoint cover of [0,2048)). Same fp-contract(off) distance
// op sequence => bitwise-same d; strict-< ascending scan = lex-(d,idx)
// top-16 per list (R8-validated); merge tree = same parameterized code
// starting at L=16 (one fewer round); explicit lex compare => global lex
// top-16 => bit-identical nn_idx. Gains: 1 fewer merge round, half the
// blocks (1024), 2 broadcast addrs/wave-iter (was 4). LDS 51.0 KB => 3
// blocks/CU (unchanged from R14).
// ---------------------------------------------------------------------------
__global__ __launch_bounds__(512) void knn_kernel(
    const float* __restrict__ xyz1, const float* __restrict__ xyz2,
    unsigned short* __restrict__ nn_idx) {
#pragma clang fp contract(off)
  __shared__ float s_cd[32][266];              // 34.0 KB (266: bank spread)
  __shared__ unsigned short s_ci[32][266];     // 17.0 KB
  const int b = blockIdx.y;
  const int q0 = blockIdx.x * 32;
  const int tid = threadIdx.x;

  const float* p1 = xyz1 + (size_t)b * N1 * 3;

  const int wv = tid >> 6;          // 0..7
  const int lane = tid & 63;
  const int q = lane & 31;          // 0..31: query within block
  const int sub = lane >> 5;        // 0..1
  const int list = wv * 2 + sub;    // 0..15
  const float* p2 = xyz2 + ((size_t)b * N2 + q0 + q) * 3;
  const float qx = p2[0], qy = p2[1], qz = p2[2];

  float bd[S];
  int bi[S];
#pragma unroll
  for (int j = 0; j < S; ++j) { bd[j] = 3.4e38f; bi[j] = 0x7fffffff; }

  for (int ii = 0; ii < 128; ++ii) {
    const int i = list + (ii << 4);   // ascending within list; disjoint lists
    float x = p1[i * 3 + 0];
    float y = p1[i * 3 + 1];
    float z = p1[i * 3 + 2];
    float dx = qx - x;
    float dy = qy - y;
    float dz = qz - z;
    float d = dx * dx;
    d = d + dy * dy;
    d = d + dz * dz;
    if (d < bd[S - 1]) {   // ascending subset scan: strict < == lex (d, idx)
      bd[S - 1] = d;
      bi[S - 1] = i;
#pragma unroll
      for (int j = S - 1; j > 0; --j) {
        if (bd[j] < bd[j - 1]) {
          float td = bd[j]; bd[j] = bd[j - 1]; bd[j - 1] = td;
          int ti = bi[j]; bi[j] = bi[j - 1]; bi[j - 1] = ti;
        }
      }
    }
  }
  {
    const int ls = list * 16;
#pragma unroll
    for (int j = 0; j < S; ++j) {
      s_cd[q][ls + j] = bd[j];
      s_ci[q][ls + j] = (unsigned short)bi[j];
    }
  }
  __syncthreads();

  // Tree merge: L lists -> L/2, in-place (slot m), barrier-separated.
  // Same parameterized code as the R8-validated kernel, starting at L=16.
  for (int L = 16; L >= 4; L >>= 1) {
    const int half = L >> 1;
    const int nact = 32 * half;
    const int valid = tid < nact;
    float od[16];
    int oi[16];
    int q2 = 0, m = 0;
    if (valid) {
      q2 = tid / half;
      m = tid - q2 * half;
      int pa = (2 * m) * 16, ea = pa + 16;
      int pb = ea, eb = pb + 16;
#pragma unroll
      for (int j = 0; j < 16; ++j) {
        const int a_ok = pa < ea, b_ok = pb < eb;
        const int ra = a_ok ? pa : ea - 1;
        const int rb = b_ok ? pb : eb - 1;
        float da = s_cd[q2][ra];
        int ia = (int)s_ci[q2][ra];
        float db = s_cd[q2][rb];
        int ib = (int)s_ci[q2][rb];
        const int ta = a_ok && (!b_ok || da < db || (da == db && ia < ib));
        od[j] = ta ? da : db;
        oi[j] = ta ? ia : ib;
        pa += ta;
        pb += !ta;
      }
    }
    __syncthreads();
    if (valid) {
#pragma unroll
      for (int j = 0; j < 16; ++j) {
        s_cd[q2][m * 16 + j] = od[j];
        s_ci[q2][m * 16 + j] = (unsigned short)oi[j];
      }
    }
    __syncthreads();
  }

  // Final round: merge lists 0,1 -> global output (32 threads).
  if (tid < 32) {
    const int q2 = tid;
    int pa = 0, ea = 16, pb = 16, eb = 32;
    unsigned short* op = nn_idx + ((size_t)b * N2 + q0 + q2) * S;
#pragma unroll
    for (int j = 0; j < 16; ++j) {
      const int a_ok = pa < ea, b_ok = pb < eb;
      const int ra = a_ok ? pa : ea - 1;
      const int rb = b_ok ? pb : eb - 1;
      float da = s_cd[q2][ra];
      int ia = (int)s_ci[q2][ra];
      float db = s_cd[q2][rb];
      int ib = (int)s_ci[q2][rb];
      const int ta = a_ok && (!b_ok || da < db || (da == db && ia < ib));
      op[j] = (unsigned short)(ta ? ia : ib);
      pa += ta;
      pb += !ta;
    }
  }
}

// ---------------------------------------------------------------------------
// Conv: VERBATIM R7 (best verified: 370 us, 112 VGPR, no spill, absmax
// 0.03125). Nine restructures (R5/R6/R8-R13) all regressed: this monolith
// at 256 threads / no reg-cap is the allocator's local optimum
// ({2 waves/SIMD x high ILP}); conv is closed at this shape.
// ---------------------------------------------------------------------------
__global__ __launch_bounds__(256) void conv_kernel(
    const float* __restrict__ xyz1, const float* __restrict__ feat1,
    const float* __restrict__ xyz2, const float* __restrict__ feat2,
    const float* __restrict__ kp, const float* __restrict__ W,
    const unsigned short* __restrict__ nn_idx, float* __restrict__ out) {
  __shared__ __align__(16) float s_buf[5184];   // 20.7 KB, aliased regions:
  int (*s_idx)[S] = (int(*)[S])(s_buf);                  // [0, 256)
  float (*s_rel)[S][3] = (float(*)[S][3])(s_buf + 256);  // [256, 1024)
  float (*s_w)[260] = (float(*)[260])(s_buf + 1024);     // [1024, 5184)
  float (*s_red)[16][132] = (float(*)[16][132])(s_buf);  // [0, 4224) alias
  __shared__ float s_wf[C1][20];               // 10 KB (live through k-loop)
  __shared__ float s_kp[K * 3];

  const int b = blockIdx.y;
  const int q0 = blockIdx.x * 16;
  const int tid = threadIdx.x;

  if (tid < K * 3) s_kp[tid] = kp[tid];
  s_idx[tid >> 4][tid & 15] = (int)nn_idx[((size_t)b * N2 + q0) * S + tid];
  __syncthreads();

  {
    int q = tid >> 4, s = tid & 15;
    int i = s_idx[q][s];
    const float* pn = xyz1 + ((size_t)b * N1 + i) * 3;
    const float* pq = xyz2 + ((size_t)b * N2 + q0 + q) * 3;
    s_rel[q][s][0] = pn[0] - pq[0];
    s_rel[q][s][1] = pn[1] - pq[1];
    s_rel[q][s][2] = pn[2] - pq[2];
  }
  __syncthreads();

  for (int t = tid; t < 16 * S * K; t += 256) {
    int q = t / (S * K);
    int r = t - q * (S * K);
    int s = r / K;
    int k = r - s * K;
    float rx = s_rel[q][s][0] - s_kp[k * 3 + 0];
    float ry = s_rel[q][s][1] - s_kp[k * 3 + 1];
    float rz = s_rel[q][s][2] - s_kp[k * 3 + 2];
    float d = sqrtf(fmaxf(rx * rx + ry * ry + rz * rz, 1e-12f));
    s_w[q][s * 16 + k] = fmaxf(0.0f, 1.0f - d / 0.2f);
  }
  __syncthreads();

  const int q = tid & 15;
  const int cg = tid >> 4;

  float wfr[K][8];
#pragma unroll
  for (int k = 0; k < K; ++k)
#pragma unroll
    for (int j = 0; j < 8; ++j) wfr[k][j] = 0.0f;

  for (int s = 0; s < S; ++s) {
    int i = s_idx[q][s];
    const float4* fp = (const float4*)(feat1 + ((size_t)b * N1 + i) * C1) + cg * 2;
    float4 n0 = fp[0];
    float4 n1 = fp[1];
    const float4* wr = (const float4*)(&s_w[q][s * 16]);
    float4 w0 = wr[0], w1 = wr[1], w2 = wr[2], w3 = wr[3];
    float wk[16] = {w0.x, w0.y, w0.z, w0.w, w1.x, w1.y, w1.z, w1.w,
                    w2.x, w2.y, w2.z, w2.w, w3.x, w3.y, w3.z, w3.w};
#pragma unroll
    for (int k = 0; k < K; ++k) {
      float w = wk[k];
      wfr[k][0] += w * n0.x;
      wfr[k][1] += w * n0.y;
      wfr[k][2] += w * n0.z;
      wfr[k][3] += w * n0.w;
      wfr[k][4] += w * n1.x;
      wfr[k][5] += w * n1.y;
      wfr[k][6] += w * n1.z;
      wfr[k][7] += w * n1.w;
    }
  }

  const int qg = tid >> 7;
  const int cs = (tid >> 5) & 3;
  const int fg = tid & 31;
  float4 acc[8];
#pragma unroll
  for (int qi = 0; qi < 8; ++qi) acc[qi] = make_float4(0.f, 0.f, 0.f, 0.f);

  for (int k = 0; k < K; ++k) {
    __syncthreads();
#pragma unroll
    for (int j = 0; j < 8; ++j) s_wf[cg * 8 + j][q] = wfr[k][j];
    __syncthreads();

    const float4* Wk4 = (const float4*)(W + (size_t)k * C1 * F) + fg;
#pragma unroll 4
    for (int c2 = 0; c2 < 32; ++c2) {
      int c = cs * 32 + c2;
      float4 wa = *(const float4*)(&s_wf[c][qg * 8 + 0]);
      float4 wb = *(const float4*)(&s_wf[c][qg * 8 + 4]);
      float4 w4 = Wk4[c * 32];
      acc[0].x += wa.x * w4.x; acc[0].y += wa.x * w4.y;
      acc[0].z += wa.x * w4.z; acc[0].w += wa.x * w4.w;
      acc[1].x += wa.y * w4.x; acc[1].y += wa.y * w4.y;
      acc[1].z += wa.y * w4.z; acc[1].w += wa.y * w4.w;
      acc[2].x += wa.z * w4.x; acc[2].y += wa.z * w4.y;
      acc[2].z += wa.z * w4.z; acc[2].w += wa.z * w4.w;
      acc[3].x += wa.w * w4.x; acc[3].y += wa.w * w4.y;
      acc[3].z += wa.w * w4.z; acc[3].w += wa.w * w4.w;
      acc[4].x += wb.x * w4.x; acc[4].y += wb.x * w4.y;
      acc[4].z += wb.x * w4.z; acc[4].w += wb.x * w4.w;
      acc[5].x += wb.y * w4.x; acc[5].y += wb.y * w4.y;
      acc[5].z += wb.y * w4.z; acc[5].w += wb.y * w4.w;
      acc[6].x += wb.z * w4.x; acc[6].y += wb.z * w4.y;
      acc[6].z += wb.z * w4.z; acc[6].w += wb.z * w4.w;
      acc[7].x += wb.w * w4.x; acc[7].y += wb.w * w4.y;
      acc[7].z += wb.w * w4.z; acc[7].w += wb.w * w4.w;
    }
  }

  // 2-pass reduction into s_red[2][16][132] (aliases s_idx/s_rel/s_w — all
  // dead, >=30 barriers before the first write here). Summation order
  // ((a0+a1)+a2)+a3 preserved => bit-identical. Validated R5-R7/R14.
  const int qq0 = tid >> 5;        // item 0: qq 0..7
  const int qq1 = 8 + (tid >> 5);  // item 1: qq 8..15
  const int fj = tid & 31;

  if (cs < 2) {
#pragma unroll
    for (int qi = 0; qi < 8; ++qi)
      *(float4*)(&s_red[cs][qg * 8 + qi][fg * 4]) = acc[qi];
  }
  __syncthreads();

  float4 s01_0, s01_1;
  {
    float4 a0 = *(const float4*)&s_red[0][qq0][fj * 4];
    float4 a1 = *(const float4*)&s_red[1][qq0][fj * 4];
    s01_0.x = a0.x + a1.x; s01_0.y = a0.y + a1.y;
    s01_0.z = a0.z + a1.z; s01_0.w = a0.w + a1.w;
    float4 b0 = *(const float4*)&s_red[0][qq1][fj * 4];
    float4 b1 = *(const float4*)&s_red[1][qq1][fj * 4];
    s01_1.x = b0.x + b1.x; s01_1.y = b0.y + b1.y;
    s01_1.z = b0.z + b1.z; s01_1.w = b0.w + b1.w;
  }
  __syncthreads();
  if (cs >= 2) {
#pragma unroll
    for (int qi = 0; qi < 8; ++qi)
      *(float4*)(&s_red[cs - 2][qg * 8 + qi][fg * 4]) = acc[qi];
  }
  __syncthreads();
  {
    float4 a2 = *(const float4*)&s_red[0][qq0][fj * 4];
    float4 a3 = *(const float4*)&s_red[1][qq0][fj * 4];
    float4 v;
    v.x = fmaxf((s01_0.x + a2.x) + a3.x, 0.0f);
    v.y = fmaxf((s01_0.y + a2.y) + a3.y, 0.0f);
    v.z = fmaxf((s01_0.z + a2.z) + a3.z, 0.0f);
    v.w = fmaxf((s01_0.w + a2.w) + a3.w, 0.0f);
    ((float4*)(out + ((size_t)b * N2 + q0 + qq0) * (F + C2)))[fj] = v;
    float4 b2 = *(const float4*)&s_red[0][qq1][fj * 4];
    float4 b3 = *(const float4*)&s_red[1][qq1][fj * 4];
    float4 u;
    u.x = fmaxf((s01_1.x + b2.x) + b3.x, 0.0f);
    u.y = fmaxf((s01_1.y + b2.y) + b3.y, 0.0f);
    u.z = fmaxf((s01_1.z + b2.z) + b3.z, 0.0f);
    u.w = fmaxf((s01_1.w + b2.w) + b3.w, 0.0f);
    ((float4*)(out + ((size_t)b * N2 + q0 + qq1) * (F + C2)))[fj] = u;
  }

  {
    int qq = tid >> 4;
    int j = tid & 15;
    float4 v = ((const float4*)(feat2 + ((size_t)b * N2 + q0 + qq) * C2))[j];
    ((float4*)(out + ((size_t)b * N2 + q0 + qq) * (F + C2) + F))[j] = v;
  }
}

extern "C" void kernel_launch(void* const* d_in, const int* in_sizes, int n_in,
                              void* d_out, int out_size, void* d_ws, size_t ws_size,
                              hipStream_t stream) {
  const float* xyz1 = (const float*)d_in[0];
  const float* feat1 = (const float*)d_in[1];
  const float* xyz2 = (const float*)d_in[2];
  const float* feat2 = (const float*)d_in[3];
  const float* kp = (const float*)d_in[4];
  const float* Wm = (const float*)d_in[5];
  float* out = (float*)d_out;

  unsigned short* nn_idx = (unsigned short*)d_ws;   // 1 MB (known-safe)

  knn_kernel<<<dim3(N2 / 32, B), 512, 0, stream>>>(xyz1, xyz2, nn_idx);
  conv_kernel<<<dim3(N2 / 16, B), 256, 0, stream>>>(xyz1, feat1, xyz2, feat2,
                                                    kp, Wm, nn_idx, out);
}